// Round 3
// baseline (3868.637 us; speedup 1.0000x reference)
//
#include <hip/hip_runtime.h>

typedef unsigned short u16;
typedef unsigned int u32;
typedef __attribute__((ext_vector_type(8))) short short8v;
typedef __attribute__((ext_vector_type(4))) float f32x4;

#define GLD_LDS(g, l) __builtin_amdgcn_global_load_lds( \
    (const __attribute__((address_space(1))) void*)(g), \
    (__attribute__((address_space(3))) void*)(l), 16, 0, 0)

#define MAGIC 0x13579BDFu

__device__ __forceinline__ u16 f2bf(float f){
  union { float f; u32 u; } v; v.f = f;
  u32 r = v.u + 0x7FFFu + ((v.u >> 16) & 1u);
  return (u16)(r >> 16);
}
__device__ __forceinline__ float bf2f(u16 h){
  union { u32 u; float f; } v; v.u = ((u32)h) << 16;
  return v.f;
}
__device__ __forceinline__ u32 pk2(float a, float b){
  return (u32)f2bf(a) | ((u32)f2bf(b) << 16);
}
__device__ __forceinline__ float sigm(float x){ return 1.f/(1.f+__expf(-x)); }
__device__ __forceinline__ float tanh_fast(float x){ return 1.f - 2.f/(1.f+__expf(2.f*x)); }

// two-level grid barrier: 8 sub-counters (64 blocks each) + root. One-shot slots.
__device__ __forceinline__ void gbar(u32* bar, int slot, bool first){
  __syncthreads();
  if (threadIdx.x == 0){
    __threadfence();
    if (first){
      while (__hip_atomic_load(bar + 48*16, __ATOMIC_ACQUIRE, __HIP_MEMORY_SCOPE_AGENT) != MAGIC)
        __builtin_amdgcn_s_sleep(1);
    }
    u32* sub  = bar + slot*16 + (blockIdx.x & 7);
    u32* root = bar + slot*16 + 8;
    if (__hip_atomic_fetch_add(sub, 1u, __ATOMIC_ACQ_REL, __HIP_MEMORY_SCOPE_AGENT) == 63u)
      __hip_atomic_fetch_add(root, 1u, __ATOMIC_ACQ_REL, __HIP_MEMORY_SCOPE_AGENT);
    while (__hip_atomic_load(root, __ATOMIC_ACQUIRE, __HIP_MEMORY_SCOPE_AGENT) != 8u)
      __builtin_amdgcn_s_sleep(1);
    __threadfence();
  }
  __syncthreads();
}

__global__ __launch_bounds__(256, 2) void mega_kernel(
    const float* past, const float* obs, const float* conv_w, const float* conv_b,
    const float* enc_w_ih, const float* enc_w_hh, const float* enc_b_ih, const float* enc_b_hh,
    const float* memory_past, const float* memory_fut,
    const float* Wq, const float* bq, const float* Wk, const float* bk,
    const float* Wv, const float* bv,
    const float* dec_w_ih, const float* dec_w_hh, const float* dec_b_ih, const float* dec_b_hh,
    const float* fc_w, const float* fc_b, float* out,
    u32* bar, float* stateP, float* qf, u16* qbB,
    float* m_part, float* l_part, float* acc_part, float* pred,
    u16* Kb, u16* Vc, u16* Dihf, u16* Dhhf)
{
  __shared__ __align__(16) char SMEM[61440];
  const int tid = threadIdx.x, bx = blockIdx.x;
  const int wid = tid>>6, lane = tid&63, qd = lane>>4, ln = lane&15;
  f32x4 zf = {0.f,0.f,0.f,0.f};

  // ---------------- barrier-slot init (block 0) ----------------
  if (bx == 0){
    for (int i = tid; i < 48*16; i += 256) bar[i] = 0;
    __syncthreads();
    if (tid == 0){
      __threadfence();
      __hip_atomic_store(bar + 48*16, MAGIC, __ATOMIC_RELEASE, __HIP_MEMORY_SCOPE_AGENT);
    }
  }

  // ---------------- phase 0a: decoder weight frag prep (all blocks) -------
  if (tid < 108){
    int which = (tid >= 54) ? 1 : 0;
    int e = bx*54 + (tid - which*54);
    const float* src = which ? dec_w_hh : dec_w_ih;
    u16* dst = which ? Dhhf : Dihf;
    int j = e&7, l2 = (e>>3)&15, q2 = (e>>7)&3, tkc = e>>9;
    int kc = tkc % 3, nt = tkc / 3;
    dst[e] = f2bf(src[(nt*16+l2)*96 + kc*32 + q2*8 + j]);
  }

  // ---------------- phase 0b: kv (blocks 0..503) / enc (504..511) ---------
  if (bx >= 504){
    // ======== ENCODER: conv1d + 8-step GRU(48) + q0, 4 waves x 16 rows ====
    int eb = bx - 504;
    u16* sWih = (u16*)(SMEM);
    u16* sWhh = (u16*)(SMEM + 18432);
    u16* sWq  = (u16*)(SMEM + 36864);
    float* sCw = (float*)(SMEM + 43008);
    float* sCb = (float*)(SMEM + 44160);
    float* sPast = (float*)(SMEM + 44352);
    u16* sHbW = (u16*)(SMEM + 48448 + wid*2304);
    // weight frags (bf16, zero-padded k 48..63)
    for (int e0 = tid; e0 < 21504; e0 += 256){
      int e = e0; const float* src; u16* dst;
      if (e < 9216){ src = enc_w_ih; dst = sWih; }
      else if (e < 18432){ e -= 9216; src = enc_w_hh; dst = sWhh; }
      else { e -= 18432; src = Wq; dst = sWq; }
      int j = e&7, l2 = (e>>3)&15, q2 = (e>>7)&3, tkc = e>>9;
      int kc = tkc&1, nt = tkc>>1;
      int g = nt*16+l2, k = kc*32+q2*8+j;
      dst[e] = (k < 48) ? f2bf(src[g*48+k]) : (u16)0;
    }
    for (int i = tid; i < 288; i += 256) sCw[i] = conv_w[i];
    if (tid < 48) sCb[tid] = conv_b[tid];
    for (int i = tid; i < 1024; i += 256) sPast[i] = past[eb*1024 + i];
    __syncthreads();
    // conv for all 8 timesteps directly into A-fragment registers
    short8v aE[8][2];
    {
      const float* pr = &sPast[(wid*16 + ln)*16];
      for (int t = 0; t < 8; ++t)
        for (int kc = 0; kc < 2; ++kc){
          union { short8v v; u16 h[8]; } u;
          #pragma unroll
          for (int j = 0; j < 8; ++j){
            int d = kc*32 + qd*8 + j;
            float a = 0.f;
            if (d < 48){
              a = sCb[d];
              #pragma unroll
              for (int kt = 0; kt < 3; ++kt){
                int tau = t + kt - 1;
                if (tau >= 0 && tau < 8){
                  a += pr[tau*2+0]*sCw[d*6+kt];
                  a += pr[tau*2+1]*sCw[d*6+3+kt];
                }
              }
              a = fmaxf(a, 0.f);
            }
            u.h[j] = (d < 48) ? f2bf(a) : (u16)0;
          }
          aE[t][kc] = u.v;
        }
    }
    // zero h buffer
    for (int i = lane; i < 576; i += 64) ((u32*)sHbW)[i] = 0;
    float biR[3],biZ[3],biN[3],bhR[3],bhZ[3],bhN[3];
    #pragma unroll
    for (int i = 0; i < 3; ++i){
      int d = i*16 + ln;
      biR[i]=enc_b_ih[d]; biZ[i]=enc_b_ih[48+d]; biN[i]=enc_b_ih[96+d];
      bhR[i]=enc_b_hh[d]; bhZ[i]=enc_b_hh[48+d]; bhN[i]=enc_b_hh[96+d];
    }
    float hreg[3][4];
    #pragma unroll
    for (int i=0;i<3;++i) for (int r=0;r<4;++r) hreg[i][r]=0.f;
    int r0 = eb*64 + wid*16;
    #pragma unroll 1
    for (int t = 0; t < 8; ++t){
      short8v aH0 = *(const short8v*)&sHbW[ln*72 + qd*8];
      short8v aH1 = *(const short8v*)&sHbW[ln*72 + 32 + qd*8];
      f32x4 gI[9], gH[9];
      #pragma unroll
      for (int nt = 0; nt < 9; ++nt){ gI[nt] = zf; gH[nt] = zf; }
      #pragma unroll
      for (int nt = 0; nt < 9; ++nt){
        gI[nt] = __builtin_amdgcn_mfma_f32_16x16x32_bf16(aE[t][0], *(const short8v*)&sWih[((nt*2+0)*4+qd)*128 + ln*8], gI[nt], 0,0,0);
        gI[nt] = __builtin_amdgcn_mfma_f32_16x16x32_bf16(aE[t][1], *(const short8v*)&sWih[((nt*2+1)*4+qd)*128 + ln*8], gI[nt], 0,0,0);
        gH[nt] = __builtin_amdgcn_mfma_f32_16x16x32_bf16(aH0, *(const short8v*)&sWhh[((nt*2+0)*4+qd)*128 + ln*8], gH[nt], 0,0,0);
        gH[nt] = __builtin_amdgcn_mfma_f32_16x16x32_bf16(aH1, *(const short8v*)&sWhh[((nt*2+1)*4+qd)*128 + ln*8], gH[nt], 0,0,0);
      }
      #pragma unroll
      for (int i3 = 0; i3 < 3; ++i3)
        #pragma unroll
        for (int r = 0; r < 4; ++r){
          float rr = sigm(gI[i3][r]+biR[i3] + gH[i3][r]+bhR[i3]);
          float zz = sigm(gI[i3+3][r]+biZ[i3] + gH[i3+3][r]+bhZ[i3]);
          float nn = tanh_fast(gI[i3+6][r]+biN[i3] + rr*(gH[i3+6][r]+bhN[i3]));
          float hv = (1.f-zz)*nn + zz*hreg[i3][r];
          hreg[i3][r] = hv;
          sHbW[(qd*4+r)*72 + i3*16 + ln] = f2bf(hv);
        }
    }
    #pragma unroll
    for (int i3 = 0; i3 < 3; ++i3)
      #pragma unroll
      for (int r = 0; r < 4; ++r)
        stateP[(r0+qd*4+r)*48 + i3*16 + ln] = hreg[i3][r];
    // q0 = h @ Wq^T + bq
    short8v aH0 = *(const short8v*)&sHbW[ln*72 + qd*8];
    short8v aH1 = *(const short8v*)&sHbW[ln*72 + 32 + qd*8];
    f32x4 q3[3];
    #pragma unroll
    for (int nt = 0; nt < 3; ++nt){
      q3[nt] = zf;
      q3[nt] = __builtin_amdgcn_mfma_f32_16x16x32_bf16(aH0, *(const short8v*)&sWq[((nt*2+0)*4+qd)*128 + ln*8], q3[nt], 0,0,0);
      q3[nt] = __builtin_amdgcn_mfma_f32_16x16x32_bf16(aH1, *(const short8v*)&sWq[((nt*2+1)*4+qd)*128 + ln*8], q3[nt], 0,0,0);
    }
    #pragma unroll
    for (int nt = 0; nt < 3; ++nt)
      #pragma unroll
      for (int r = 0; r < 4; ++r){
        int row = r0 + qd*4 + r, d = nt*16 + ln;
        float v = q3[nt][r] + bq[d];
        qf[row*48 + d] = v;
        qbB[row*64 + d] = f2bf(v);
      }
    #pragma unroll
    for (int r = 0; r < 4; ++r)
      if (ln < 8) *(u32*)&qbB[(r0+qd*4+r)*64 + 48 + ln*2] = 0;
  } else {
    // ======== KV projection: 64 keys per tile ========
    u16* sWkF = (u16*)(SMEM);
    u16* sWvF = (u16*)(SMEM + 6144);
    u16* smp  = (u16*)(SMEM + 12288 + wid*2304);
    u16* smf  = (u16*)(SMEM + 21504 + wid*2304);
    for (int e0 = tid; e0 < 6144; e0 += 256){
      int e = e0; const float* src; u16* dst;
      if (e < 3072){ src = Wk; dst = sWkF; } else { e -= 3072; src = Wv; dst = sWvF; }
      int j = e&7, l2 = (e>>3)&15, q2 = (e>>7)&3, tkc = e>>9;
      int kc = tkc&1, nt = tkc>>1;
      int g = nt*16+l2, k = kc*32+q2*8+j;
      dst[e] = (k < 48) ? f2bf(src[g*48+k]) : (u16)0;
    }
    __syncthreads();
    int ntile = (bx < 8) ? 2 : 1;
    for (int tt = 0; tt < ntile; ++tt){
      int tile = (tt == 0) ? bx : (504 + bx);
      int r0 = tile*64 + wid*16;
      for (int i = lane; i < 576; i += 64){ ((u32*)smp)[i] = 0; ((u32*)smf)[i] = 0; }
      for (int i = lane; i < 768; i += 64){
        int r = i/48, c = i - r*48;
        smp[r*72+c] = f2bf(memory_past[(size_t)r0*48 + i]);
        smf[r*72+c] = f2bf(memory_fut[(size_t)r0*48 + i]);
      }
      short8v aP0 = *(const short8v*)&smp[ln*72 + qd*8];
      short8v aP1 = *(const short8v*)&smp[ln*72 + 32 + qd*8];
      short8v aF0 = *(const short8v*)&smf[ln*72 + qd*8];
      short8v aF1 = *(const short8v*)&smf[ln*72 + 32 + qd*8];
      f32x4 k3[3], v3[3];
      #pragma unroll
      for (int nt = 0; nt < 3; ++nt){ k3[nt] = zf; v3[nt] = zf; }
      #pragma unroll
      for (int nt = 0; nt < 3; ++nt){
        k3[nt] = __builtin_amdgcn_mfma_f32_16x16x32_bf16(aP0, *(const short8v*)&sWkF[((nt*2+0)*4+qd)*128 + ln*8], k3[nt], 0,0,0);
        k3[nt] = __builtin_amdgcn_mfma_f32_16x16x32_bf16(aP1, *(const short8v*)&sWkF[((nt*2+1)*4+qd)*128 + ln*8], k3[nt], 0,0,0);
        v3[nt] = __builtin_amdgcn_mfma_f32_16x16x32_bf16(aF0, *(const short8v*)&sWvF[((nt*2+0)*4+qd)*128 + ln*8], v3[nt], 0,0,0);
        v3[nt] = __builtin_amdgcn_mfma_f32_16x16x32_bf16(aF1, *(const short8v*)&sWvF[((nt*2+1)*4+qd)*128 + ln*8], v3[nt], 0,0,0);
      }
      #pragma unroll
      for (int nt = 0; nt < 3; ++nt)
        #pragma unroll
        for (int r = 0; r < 4; ++r){
          int key = r0 + qd*4 + r, d = nt*16 + ln;
          Kb[(size_t)key*64 + d] = f2bf(k3[nt][r] + bk[d]);
          int ch = key >> 9, kt = (key >> 6) & 7, kin = key & 63;
          Vc[(size_t)(((ch*8 + kt)*48 + d))*64 + kin] = f2bf(v3[nt][r] + bv[d]);
        }
      #pragma unroll
      for (int r = 0; r < 4; ++r)
        if (ln < 8){ int key = r0 + qd*4 + r; *(u32*)&Kb[(size_t)key*64 + 48 + ln*2] = 0; }
    }
  }

  gbar(bar, 0, true);

  // ---------------- 20 attention iterations ----------------
  const int rg = bx >> 6, ch = bx & 63;
  #pragma unroll 1
  for (int it = 0; it < 20; ++it){
    { // ===== FLASH: S^T = K q^T, O^T = V^T P^T; 8 key-tiles of 64, dbuf LDS =====
      int rowbase = rg*64 + wid*16;
      u16* sp = (u16*)(SMEM + 28672 + wid*2304);
      short8v aq0 = *(const short8v*)(qbB + (rowbase+ln)*64 + qd*8);
      short8v aq1 = *(const short8v*)(qbB + (rowbase+ln)*64 + 32 + qd*8);
      f32x4 acc[3] = {zf, zf, zf};
      float mrun = -3.0e38f, lrun = 0.f;
      // stage kt=0
      {
        const char* ks = (const char*)(Kb + (size_t)(ch*512)*64);
        GLD_LDS(ks + (wid*2+0)*1024 + lane*16, SMEM + (wid*2+0)*1024);
        GLD_LDS(ks + (wid*2+1)*1024 + lane*16, SMEM + (wid*2+1)*1024);
        const char* vs = (const char*)(Vc + (size_t)(ch*8*48)*64);
        for (int c = wid; c < 6; c += 4)
          GLD_LDS(vs + c*1024 + lane*16, SMEM + 16384 + c*1024);
      }
      __syncthreads();
      #pragma unroll 1
      for (int kt = 0; kt < 8; ++kt){
        int cur = kt & 1;
        if (kt < 7){
          int nb = cur ^ 1;
          const char* ks = (const char*)(Kb + (size_t)(ch*512 + (kt+1)*64)*64);
          GLD_LDS(ks + (wid*2+0)*1024 + lane*16, SMEM + nb*8192 + (wid*2+0)*1024);
          GLD_LDS(ks + (wid*2+1)*1024 + lane*16, SMEM + nb*8192 + (wid*2+1)*1024);
          const char* vs = (const char*)(Vc + (size_t)((ch*8 + kt+1)*48)*64);
          for (int c = wid; c < 6; c += 4)
            GLD_LDS(vs + c*1024 + lane*16, SMEM + 16384 + nb*6144 + c*1024);
        }
        const u16* kb = (const u16*)(SMEM + cur*8192);
        const u16* vb = (const u16*)(SMEM + 16384 + cur*6144);
        f32x4 s[4];
        #pragma unroll
        for (int nt = 0; nt < 4; ++nt){
          f32x4 z = zf;
          z = __builtin_amdgcn_mfma_f32_16x16x32_bf16(*(const short8v*)&kb[(nt*16+ln)*64 + qd*8], aq0, z, 0,0,0);
          z = __builtin_amdgcn_mfma_f32_16x16x32_bf16(*(const short8v*)&kb[(nt*16+ln)*64 + 32 + qd*8], aq1, z, 0,0,0);
          s[nt] = z;
        }
        float vmax = s[0][0];
        #pragma unroll
        for (int nt = 0; nt < 4; ++nt)
          #pragma unroll
          for (int r = 0; r < 4; ++r) vmax = fmaxf(vmax, s[nt][r]);
        vmax = fmaxf(vmax, __shfl_xor(vmax, 16));
        vmax = fmaxf(vmax, __shfl_xor(vmax, 32));
        float mnew = fmaxf(mrun, vmax);
        float alpha = __expf(mrun - mnew);
        mrun = mnew;
        float lsum = 0.f;
        #pragma unroll
        for (int nt = 0; nt < 4; ++nt){
          float p0 = __expf(s[nt][0]-mnew), p1 = __expf(s[nt][1]-mnew);
          float p2 = __expf(s[nt][2]-mnew), p3 = __expf(s[nt][3]-mnew);
          lsum += (p0+p1)+(p2+p3);
          uint2 pk; pk.x = pk2(p0,p1); pk.y = pk2(p2,p3);
          *(uint2*)&sp[ln*72 + nt*16 + qd*4] = pk;
        }
        lsum += __shfl_xor(lsum, 16);
        lsum += __shfl_xor(lsum, 32);
        lrun = lrun*alpha + lsum;
        #pragma unroll
        for (int dt = 0; dt < 3; ++dt){
          acc[dt][0] *= alpha; acc[dt][1] *= alpha; acc[dt][2] *= alpha; acc[dt][3] *= alpha;
        }
        short8v pb0 = *(const short8v*)&sp[ln*72 + qd*8];
        short8v pb1 = *(const short8v*)&sp[ln*72 + 32 + qd*8];
        #pragma unroll
        for (int dt = 0; dt < 3; ++dt){
          acc[dt] = __builtin_amdgcn_mfma_f32_16x16x32_bf16(*(const short8v*)&vb[(dt*16+ln)*64 + qd*8], pb0, acc[dt], 0,0,0);
          acc[dt] = __builtin_amdgcn_mfma_f32_16x16x32_bf16(*(const short8v*)&vb[(dt*16+ln)*64 + 32 + qd*8], pb1, acc[dt], 0,0,0);
        }
        __syncthreads();
      }
      int row = rowbase + ln;
      if (lane < 16){
        m_part[row*64 + ch] = mrun;
        l_part[row*64 + ch] = lrun;
      }
      #pragma unroll
      for (int dt = 0; dt < 3; ++dt)
        *(f32x4*)(acc_part + (size_t)(row*64 + ch)*48 + dt*16 + qd*4) = acc[dt];
    }
    gbar(bar, 1 + 2*it, false);
    { // ===== COMBINE (block = row) =====
      float* sEw  = (float*)(SMEM);
      float* sL   = (float*)(SMEM + 256);
      float* sAtt = (float*)(SMEM + 512);
      float* sC   = (float*)(SMEM + 1280);
      int row = bx;
      if (tid < 64){ sEw[tid] = m_part[row*64 + tid]; sL[tid] = l_part[row*64 + tid]; }
      __syncthreads();
      float mg = -3.0e38f;
      #pragma unroll 8
      for (int c = 0; c < 64; ++c) mg = fmaxf(mg, sEw[c]);
      __syncthreads();
      if (tid < 64) sEw[tid] = __expf(sEw[tid] - mg);
      __syncthreads();
      float lg = 0.f;
      #pragma unroll 8
      for (int c = 0; c < 64; ++c) lg += sEw[c]*sL[c];
      int qq = tid >> 6, d = tid & 63;
      if (d < 48){
        float att = 0.f;
        #pragma unroll 4
        for (int c = qq*16; c < qq*16 + 16; ++c)
          att += sEw[c]*acc_part[(size_t)(row*64 + c)*48 + d];
        sAtt[qq*48 + d] = att;
      }
      __syncthreads();
      if (qq == 0 && d < 48){
        float a = (sAtt[d] + sAtt[48+d] + sAtt[96+d] + sAtt[144+d]) / lg;
        pred[(row*20 + it)*48 + d] = a;
        sC[d] = qf[row*48 + d] + a;
      }
      __syncthreads();
      if (qq == 0){
        if (d < 48){
          float a = bq[d];
          #pragma unroll 8
          for (int k = 0; k < 48; ++k) a += sC[k]*Wq[d*48 + k];
          qf[row*48 + d] = a;
          qbB[row*64 + d] = f2bf(a);
        } else {
          qbB[row*64 + d] = 0;
        }
      }
    }
    gbar(bar, 2 + 2*it, false);
  }

  // ---------------- decoder: 12-step GRU(96), blocks 0..319, waves 0..1 ----
  if (bx < 320){
    u16* sW = (u16*)(SMEM);
    for (int i = wid; i < 54; i += 4)
      GLD_LDS((const char*)Dhhf + i*1024 + lane*16, SMEM + i*1024);
    __syncthreads();
    if (wid < 2){
      u16* sx = (u16*)(SMEM + 55296 + wid*3072);
      int rw = (bx*2 + wid)*16;
      // stage x0 = [stateP | pred]
      {
        int r = lane >> 2, k0 = (lane & 3)*24;
        int row = rw + r, b20 = row/20;
        for (int jj = 0; jj < 24; ++jj){
          int k = k0 + jj;
          float v = (k < 48) ? stateP[b20*48 + k] : pred[row*48 + (k-48)];
          sx[r*96 + k] = f2bf(v);
        }
      }
      float fw0[6], fw1[6];
      float biR[6],biZ[6],biN[6],bhR[6],bhZ[6],bhN[6];
      #pragma unroll
      for (int i = 0; i < 6; ++i){
        int d = i*16 + ln;
        fw0[i] = fc_w[d]; fw1[i] = fc_w[96+d];
        biR[i]=dec_b_ih[d]; biZ[i]=dec_b_ih[96+d]; biN[i]=dec_b_ih[192+d];
        bhR[i]=dec_b_hh[d]; bhZ[i]=dec_b_hh[96+d]; bhN[i]=dec_b_hh[192+d];
      }
      float fcb0 = fc_b[0], fcb1 = fc_b[1];
      float pr0[4], pr1[4];
      #pragma unroll
      for (int r = 0; r < 4; ++r){
        int b20 = (rw + qd*4 + r)/20;
        pr0[r] = obs[b20*16 + 14];
        pr1[r] = obs[b20*16 + 15];
      }
      #pragma unroll 1
      for (int t = 0; t < 12; ++t){
        short8v xa0 = *(const short8v*)&sx[ln*96 + qd*8];
        short8v xa1 = *(const short8v*)&sx[ln*96 + 32 + qd*8];
        short8v xa2 = *(const short8v*)&sx[ln*96 + 64 + qd*8];
        f32x4 acc[18];
        #pragma unroll
        for (int i = 0; i < 18; ++i) acc[i] = zf;
        if (t == 0){
          #pragma unroll
          for (int nt = 0; nt < 18; ++nt){
            acc[nt] = __builtin_amdgcn_mfma_f32_16x16x32_bf16(xa0, *(const short8v*)&Dihf[((nt*3+0)*4+qd)*128 + ln*8], acc[nt], 0,0,0);
            acc[nt] = __builtin_amdgcn_mfma_f32_16x16x32_bf16(xa1, *(const short8v*)&Dihf[((nt*3+1)*4+qd)*128 + ln*8], acc[nt], 0,0,0);
            acc[nt] = __builtin_amdgcn_mfma_f32_16x16x32_bf16(xa2, *(const short8v*)&Dihf[((nt*3+2)*4+qd)*128 + ln*8], acc[nt], 0,0,0);
          }
        } else {
          #pragma unroll
          for (int nt = 0; nt < 18; ++nt){
            acc[nt] = __builtin_amdgcn_mfma_f32_16x16x32_bf16(xa0, *(const short8v*)&sW[((nt*3+0)*4+qd)*128 + ln*8], acc[nt], 0,0,0);
            acc[nt] = __builtin_amdgcn_mfma_f32_16x16x32_bf16(xa1, *(const short8v*)&sW[((nt*3+1)*4+qd)*128 + ln*8], acc[nt], 0,0,0);
            acc[nt] = __builtin_amdgcn_mfma_f32_16x16x32_bf16(xa2, *(const short8v*)&sW[((nt*3+2)*4+qd)*128 + ln*8], acc[nt], 0,0,0);
          }
        }
        float px[4] = {0,0,0,0}, py[4] = {0,0,0,0};
        #pragma unroll
        for (int r = 0; r < 4; ++r)
          #pragma unroll
          for (int i = 0; i < 6; ++i){
            int d = i*16 + ln;
            float rr = sigm(acc[i][r]   + biR[i] + bhR[i]);
            float zz = sigm(acc[i+6][r] + biZ[i] + bhZ[i]);
            float nn;
            float hold;
            if (t == 0){
              nn = tanh_fast(acc[i+12][r] + biN[i] + rr*bhN[i]);
              hold = 0.f;
            } else {
              nn = tanh_fast(biN[i] + rr*(acc[i+12][r] + bhN[i]));
              hold = bf2f(sx[(qd*4+r)*96 + d]);
            }
            float hv = (1.f-zz)*nn + zz*hold;
            sx[(qd*4+r)*96 + d] = f2bf(hv);
            px[r] += fw0[i]*hv;
            py[r] += fw1[i]*hv;
          }
        #pragma unroll
        for (int msk = 8; msk >= 1; msk >>= 1)
          #pragma unroll
          for (int r = 0; r < 4; ++r){
            px[r] += __shfl_xor(px[r], msk);
            py[r] += __shfl_xor(py[r], msk);
          }
        #pragma unroll
        for (int r = 0; r < 4; ++r){
          pr0[r] += px[r] + fcb0;
          pr1[r] += py[r] + fcb1;
        }
        if (ln == 0){
          #pragma unroll
          for (int r = 0; r < 4; ++r){
            int row = rw + qd*4 + r;
            out[(row*12 + t)*2 + 0] = pr0[r];
            out[(row*12 + t)*2 + 1] = pr1[r];
          }
        }
      }
    }
  }
}

// ---------------------------------------------------------------------------
extern "C" void kernel_launch(void* const* d_in, const int* in_sizes, int n_in,
                              void* d_out, int out_size, void* d_ws, size_t ws_size,
                              hipStream_t stream)
{
  const float* past        = (const float*)d_in[0];
  const float* obs         = (const float*)d_in[1];
  const float* conv_w      = (const float*)d_in[2];
  const float* conv_b      = (const float*)d_in[3];
  const float* enc_w_ih    = (const float*)d_in[4];
  const float* enc_w_hh    = (const float*)d_in[5];
  const float* enc_b_ih    = (const float*)d_in[6];
  const float* enc_b_hh    = (const float*)d_in[7];
  const float* memory_past = (const float*)d_in[8];
  const float* memory_fut  = (const float*)d_in[9];
  const float* Wq = (const float*)d_in[10];
  const float* bq = (const float*)d_in[11];
  const float* Wk = (const float*)d_in[12];
  const float* bk = (const float*)d_in[13];
  const float* Wv = (const float*)d_in[14];
  const float* bv = (const float*)d_in[15];
  const float* dec_w_ih = (const float*)d_in[16];
  const float* dec_w_hh = (const float*)d_in[17];
  const float* dec_b_ih = (const float*)d_in[18];
  const float* dec_b_hh = (const float*)d_in[19];
  const float* fc_w = (const float*)d_in[20];
  const float* fc_b = (const float*)d_in[21];
  float* out = (float*)d_out;

  char* ws = (char*)d_ws;
  size_t off = 0;
  auto alloc = [&](size_t bytes){ void* p = ws + off; off += (bytes + 255) & ~(size_t)255; return p; };
  u32*   bar      = (u32*)alloc((48*16 + 1)*4);
  float* stateP   = (float*)alloc(512*48*4);
  float* qf       = (float*)alloc(512*48*4);
  u16*   qbB      = (u16*)alloc(512*64*2);
  float* m_part   = (float*)alloc(512*64*4);
  float* l_part   = (float*)alloc(512*64*4);
  float* acc_part = (float*)alloc((size_t)512*64*48*4);
  float* pred     = (float*)alloc((size_t)10240*48*4);
  u16*   Kb       = (u16*)alloc((size_t)32768*64*2);
  u16*   Vc       = (u16*)alloc((size_t)32768*48*2);
  u16*   Dihf     = (u16*)alloc(27648*2);
  u16*   Dhhf     = (u16*)alloc(27648*2);

  mega_kernel<<<512, 256, 0, stream>>>(
      past, obs, conv_w, conv_b, enc_w_ih, enc_w_hh, enc_b_ih, enc_b_hh,
      memory_past, memory_fut, Wq, bq, Wk, bk, Wv, bv,
      dec_w_ih, dec_w_hh, dec_b_ih, dec_b_hh, fc_w, fc_b, out,
      bar, stateP, qf, qbB, m_part, l_part, acc_part, pred,
      Kb, Vc, Dihf, Dhhf);
}

// Round 4
// 994.378 us; speedup vs baseline: 3.8905x; 3.8905x over previous
//
#include <hip/hip_runtime.h>

typedef unsigned short u16;
typedef unsigned int u32;
typedef __attribute__((ext_vector_type(8))) short short8v;
typedef __attribute__((ext_vector_type(4))) float f32x4;

#define GLD_LDS(g, l) __builtin_amdgcn_global_load_lds( \
    (const __attribute__((address_space(1))) void*)(g), \
    (__attribute__((address_space(3))) void*)(l), 16, 0, 0)

__device__ __forceinline__ u16 f2bf(float f){
  union { float f; u32 u; } v; v.f = f;
  u32 r = v.u + 0x7FFFu + ((v.u >> 16) & 1u);
  return (u16)(r >> 16);
}
__device__ __forceinline__ float bf2f(u16 h){
  union { u32 u; float f; } v; v.u = ((u32)h) << 16;
  return v.f;
}
__device__ __forceinline__ u32 pk2(float a, float b){
  return (u32)f2bf(a) | ((u32)f2bf(b) << 16);
}
__device__ __forceinline__ float sigm(float x){ return 1.f/(1.f+__expf(-x)); }
__device__ __forceinline__ float tanh_fast(float x){ return 1.f - 2.f/(1.f+__expf(2.f*x)); }

// ---------------------------------------------------------------------------
// setup: dec weight frags (all blocks) + KV projection (blocks 0..503) +
// encoder conv+GRU+q0 (blocks 504..511). Proven logic from round 3 phase 0.
__global__ __launch_bounds__(256) void setup_kernel(
    const float* past, const float* conv_w, const float* conv_b,
    const float* enc_w_ih, const float* enc_w_hh, const float* enc_b_ih, const float* enc_b_hh,
    const float* memory_past, const float* memory_fut,
    const float* Wq, const float* bq, const float* Wk, const float* bk,
    const float* Wv, const float* bv,
    const float* dec_w_ih, const float* dec_w_hh,
    float* stateP, float* qf, u16* qbB,
    u16* Kb, u16* Vc, u16* Dihf, u16* Dhhf)
{
  __shared__ __align__(16) char SMEM[61440];
  const int tid = threadIdx.x, bx = blockIdx.x;
  const int wid = tid>>6, lane = tid&63, qd = lane>>4, ln = lane&15;
  f32x4 zf = {0.f,0.f,0.f,0.f};

  // decoder weight frag prep (spread over all blocks)
  if (tid < 108){
    int which = (tid >= 54) ? 1 : 0;
    int e = bx*54 + (tid - which*54);
    const float* src = which ? dec_w_hh : dec_w_ih;
    u16* dst = which ? Dhhf : Dihf;
    int j = e&7, l2 = (e>>3)&15, q2 = (e>>7)&3, tkc = e>>9;
    int kc = tkc % 3, nt = tkc / 3;
    dst[e] = f2bf(src[(nt*16+l2)*96 + kc*32 + q2*8 + j]);
  }

  if (bx >= 504){
    // ======== ENCODER ========
    int eb = bx - 504;
    u16* sWih = (u16*)(SMEM);
    u16* sWhh = (u16*)(SMEM + 18432);
    u16* sWq  = (u16*)(SMEM + 36864);
    float* sCw = (float*)(SMEM + 43008);
    float* sCb = (float*)(SMEM + 44160);
    float* sPast = (float*)(SMEM + 44352);
    u16* sHbW = (u16*)(SMEM + 48448 + wid*2304);
    for (int e0 = tid; e0 < 21504; e0 += 256){
      int e = e0; const float* src; u16* dst;
      if (e < 9216){ src = enc_w_ih; dst = sWih; }
      else if (e < 18432){ e -= 9216; src = enc_w_hh; dst = sWhh; }
      else { e -= 18432; src = Wq; dst = sWq; }
      int j = e&7, l2 = (e>>3)&15, q2 = (e>>7)&3, tkc = e>>9;
      int kc = tkc&1, nt = tkc>>1;
      int g = nt*16+l2, k = kc*32+q2*8+j;
      dst[e] = (k < 48) ? f2bf(src[g*48+k]) : (u16)0;
    }
    for (int i = tid; i < 288; i += 256) sCw[i] = conv_w[i];
    if (tid < 48) sCb[tid] = conv_b[tid];
    for (int i = tid; i < 1024; i += 256) sPast[i] = past[eb*1024 + i];
    __syncthreads();
    short8v aE[8][2];
    {
      const float* pr = &sPast[(wid*16 + ln)*16];
      for (int t = 0; t < 8; ++t)
        for (int kc = 0; kc < 2; ++kc){
          union { short8v v; u16 h[8]; } u;
          #pragma unroll
          for (int j = 0; j < 8; ++j){
            int d = kc*32 + qd*8 + j;
            float a = 0.f;
            if (d < 48){
              a = sCb[d];
              #pragma unroll
              for (int kt = 0; kt < 3; ++kt){
                int tau = t + kt - 1;
                if (tau >= 0 && tau < 8){
                  a += pr[tau*2+0]*sCw[d*6+kt];
                  a += pr[tau*2+1]*sCw[d*6+3+kt];
                }
              }
              a = fmaxf(a, 0.f);
            }
            u.h[j] = (d < 48) ? f2bf(a) : (u16)0;
          }
          aE[t][kc] = u.v;
        }
    }
    for (int i = lane; i < 576; i += 64) ((u32*)sHbW)[i] = 0;
    float biR[3],biZ[3],biN[3],bhR[3],bhZ[3],bhN[3];
    #pragma unroll
    for (int i = 0; i < 3; ++i){
      int d = i*16 + ln;
      biR[i]=enc_b_ih[d]; biZ[i]=enc_b_ih[48+d]; biN[i]=enc_b_ih[96+d];
      bhR[i]=enc_b_hh[d]; bhZ[i]=enc_b_hh[48+d]; bhN[i]=enc_b_hh[96+d];
    }
    float hreg[3][4];
    #pragma unroll
    for (int i=0;i<3;++i) for (int r=0;r<4;++r) hreg[i][r]=0.f;
    int r0 = eb*64 + wid*16;
    #pragma unroll 1
    for (int t = 0; t < 8; ++t){
      short8v aH0 = *(const short8v*)&sHbW[ln*72 + qd*8];
      short8v aH1 = *(const short8v*)&sHbW[ln*72 + 32 + qd*8];
      f32x4 gI[9], gH[9];
      #pragma unroll
      for (int nt = 0; nt < 9; ++nt){ gI[nt] = zf; gH[nt] = zf; }
      #pragma unroll
      for (int nt = 0; nt < 9; ++nt){
        gI[nt] = __builtin_amdgcn_mfma_f32_16x16x32_bf16(aE[t][0], *(const short8v*)&sWih[((nt*2+0)*4+qd)*128 + ln*8], gI[nt], 0,0,0);
        gI[nt] = __builtin_amdgcn_mfma_f32_16x16x32_bf16(aE[t][1], *(const short8v*)&sWih[((nt*2+1)*4+qd)*128 + ln*8], gI[nt], 0,0,0);
        gH[nt] = __builtin_amdgcn_mfma_f32_16x16x32_bf16(aH0, *(const short8v*)&sWhh[((nt*2+0)*4+qd)*128 + ln*8], gH[nt], 0,0,0);
        gH[nt] = __builtin_amdgcn_mfma_f32_16x16x32_bf16(aH1, *(const short8v*)&sWhh[((nt*2+1)*4+qd)*128 + ln*8], gH[nt], 0,0,0);
      }
      #pragma unroll
      for (int i3 = 0; i3 < 3; ++i3)
        #pragma unroll
        for (int r = 0; r < 4; ++r){
          float rr = sigm(gI[i3][r]+biR[i3] + gH[i3][r]+bhR[i3]);
          float zz = sigm(gI[i3+3][r]+biZ[i3] + gH[i3+3][r]+bhZ[i3]);
          float nn = tanh_fast(gI[i3+6][r]+biN[i3] + rr*(gH[i3+6][r]+bhN[i3]));
          float hv = (1.f-zz)*nn + zz*hreg[i3][r];
          hreg[i3][r] = hv;
          sHbW[(qd*4+r)*72 + i3*16 + ln] = f2bf(hv);
        }
    }
    #pragma unroll
    for (int i3 = 0; i3 < 3; ++i3)
      #pragma unroll
      for (int r = 0; r < 4; ++r)
        stateP[(r0+qd*4+r)*48 + i3*16 + ln] = hreg[i3][r];
    short8v aH0 = *(const short8v*)&sHbW[ln*72 + qd*8];
    short8v aH1 = *(const short8v*)&sHbW[ln*72 + 32 + qd*8];
    f32x4 q3[3];
    #pragma unroll
    for (int nt = 0; nt < 3; ++nt){
      q3[nt] = zf;
      q3[nt] = __builtin_amdgcn_mfma_f32_16x16x32_bf16(aH0, *(const short8v*)&sWq[((nt*2+0)*4+qd)*128 + ln*8], q3[nt], 0,0,0);
      q3[nt] = __builtin_amdgcn_mfma_f32_16x16x32_bf16(aH1, *(const short8v*)&sWq[((nt*2+1)*4+qd)*128 + ln*8], q3[nt], 0,0,0);
    }
    #pragma unroll
    for (int nt = 0; nt < 3; ++nt)
      #pragma unroll
      for (int r = 0; r < 4; ++r){
        int row = r0 + qd*4 + r, d = nt*16 + ln;
        float v = q3[nt][r] + bq[d];
        qf[row*48 + d] = v;
        qbB[row*64 + d] = f2bf(v);
      }
    #pragma unroll
    for (int r = 0; r < 4; ++r)
      if (ln < 8) *(u32*)&qbB[(r0+qd*4+r)*64 + 48 + ln*2] = 0;
  } else {
    // ======== KV projection ========
    u16* sWkF = (u16*)(SMEM);
    u16* sWvF = (u16*)(SMEM + 6144);
    u16* smp  = (u16*)(SMEM + 12288 + wid*2304);
    u16* smf  = (u16*)(SMEM + 21504 + wid*2304);
    for (int e0 = tid; e0 < 6144; e0 += 256){
      int e = e0; const float* src; u16* dst;
      if (e < 3072){ src = Wk; dst = sWkF; } else { e -= 3072; src = Wv; dst = sWvF; }
      int j = e&7, l2 = (e>>3)&15, q2 = (e>>7)&3, tkc = e>>9;
      int kc = tkc&1, nt = tkc>>1;
      int g = nt*16+l2, k = kc*32+q2*8+j;
      dst[e] = (k < 48) ? f2bf(src[g*48+k]) : (u16)0;
    }
    __syncthreads();
    int ntile = (bx < 8) ? 2 : 1;
    for (int tt = 0; tt < ntile; ++tt){
      int tile = (tt == 0) ? bx : (504 + bx);
      int r0 = tile*64 + wid*16;
      for (int i = lane; i < 576; i += 64){ ((u32*)smp)[i] = 0; ((u32*)smf)[i] = 0; }
      for (int i = lane; i < 768; i += 64){
        int r = i/48, c = i - r*48;
        smp[r*72+c] = f2bf(memory_past[(size_t)r0*48 + i]);
        smf[r*72+c] = f2bf(memory_fut[(size_t)r0*48 + i]);
      }
      short8v aP0 = *(const short8v*)&smp[ln*72 + qd*8];
      short8v aP1 = *(const short8v*)&smp[ln*72 + 32 + qd*8];
      short8v aF0 = *(const short8v*)&smf[ln*72 + qd*8];
      short8v aF1 = *(const short8v*)&smf[ln*72 + 32 + qd*8];
      f32x4 k3[3], v3[3];
      #pragma unroll
      for (int nt = 0; nt < 3; ++nt){ k3[nt] = zf; v3[nt] = zf; }
      #pragma unroll
      for (int nt = 0; nt < 3; ++nt){
        k3[nt] = __builtin_amdgcn_mfma_f32_16x16x32_bf16(aP0, *(const short8v*)&sWkF[((nt*2+0)*4+qd)*128 + ln*8], k3[nt], 0,0,0);
        k3[nt] = __builtin_amdgcn_mfma_f32_16x16x32_bf16(aP1, *(const short8v*)&sWkF[((nt*2+1)*4+qd)*128 + ln*8], k3[nt], 0,0,0);
        v3[nt] = __builtin_amdgcn_mfma_f32_16x16x32_bf16(aF0, *(const short8v*)&sWvF[((nt*2+0)*4+qd)*128 + ln*8], v3[nt], 0,0,0);
        v3[nt] = __builtin_amdgcn_mfma_f32_16x16x32_bf16(aF1, *(const short8v*)&sWvF[((nt*2+1)*4+qd)*128 + ln*8], v3[nt], 0,0,0);
      }
      #pragma unroll
      for (int nt = 0; nt < 3; ++nt)
        #pragma unroll
        for (int r = 0; r < 4; ++r){
          int key = r0 + qd*4 + r, d = nt*16 + ln;
          Kb[(size_t)key*64 + d] = f2bf(k3[nt][r] + bk[d]);
          Vc[((size_t)(key>>8)*48 + d)*256 + (key&255)] = f2bf(v3[nt][r] + bv[d]);
        }
      #pragma unroll
      for (int r = 0; r < 4; ++r)
        if (ln < 8){ int key = r0 + qd*4 + r; *(u32*)&Kb[(size_t)key*64 + 48 + ln*2] = 0; }
    }
  }
}

// ---------------------------------------------------------------------------
// iter kernel: [combine prev partials -> pred/q] then [flash partials cur].
// mode 0: first (q from qbB, no combine); mode 1: middle; mode 2: combine-only.
// grid 512 = 32 rowgroups(16 rows) x 16 chunks(2048 keys); ch=bx&15 -> same-
// chunk blocks share an XCD's L2. mode 2: grid 32.
__global__ __launch_bounds__(256, 2) void iter_kernel(int mode, int it,
    const u16* qbB, const u16* Kb, const u16* Vc, const float* Wq, const float* bq,
    const float* qfP, float* qfC, float* pred,
    const float* mP, const float* lP, const float* aP,
    float* mC, float* lC, float* aC)
{
  __shared__ __align__(16) u16 sQ[16*64];
  __shared__ __align__(16) u16 sp4[4][16*72];
  __shared__ float sMg[4][16*50];
  __shared__ float sWc[16*16];
  __shared__ float sLg[16];
  __shared__ float sC[16*48];
  const int tid = threadIdx.x, bx = blockIdx.x;
  const int wid = tid>>6, lane = tid&63, qd = lane>>4, ln = lane&15;
  int rg, ch;
  if (mode == 2){ rg = bx; ch = 0; } else { rg = bx>>4; ch = bx&15; }
  const int rowbase = rg*16;
  f32x4 zf = {0.f,0.f,0.f,0.f};

  if (mode >= 1){
    // ---- combine previous iteration's partials ----
    int row = tid>>4, j = tid&15;
    int grow = rowbase + row;
    float m = mP[grow*16 + j], l = lP[grow*16 + j];
    float mg = m;
    #pragma unroll
    for (int k = 1; k < 16; k <<= 1) mg = fmaxf(mg, __shfl_xor(mg, k));
    float w = __expf(m - mg);
    float wl = w*l;
    #pragma unroll
    for (int k = 1; k < 16; k <<= 1) wl += __shfl_xor(wl, k);
    sWc[row*16 + j] = w;
    if (j == 0) sLg[row] = wl;
    __syncthreads();
    #pragma unroll
    for (int k = 0; k < 3; ++k){
      int d = j + k*16;
      float a = 0.f;
      #pragma unroll 4
      for (int c = 0; c < 16; ++c) a += sWc[row*16+c]*aP[(size_t)(grow*16+c)*48 + d];
      a /= sLg[row];
      if (ch == 0) pred[(size_t)(grow*20 + (it-1))*48 + d] = a;
      sC[row*48 + d] = qfP[grow*48 + d] + a;
    }
    __syncthreads();
    if (mode == 2) return;
    #pragma unroll
    for (int k = 0; k < 3; ++k){
      int d2 = j + k*16;
      float a = bq[d2];
      #pragma unroll 8
      for (int kk = 0; kk < 48; ++kk) a += sC[row*48+kk]*Wq[d2*48+kk];
      if (ch == 0) qfC[grow*48 + d2] = a;
      sQ[row*64 + d2] = f2bf(a);
    }
    if (tid < 128){ int r2 = tid>>3, p = tid&7; ((u32*)sQ)[r2*32 + 24 + p] = 0; }
    __syncthreads();
  } else {
    const u32* src = (const u32*)(qbB + rowbase*64);
    ((u32*)sQ)[tid] = src[tid];
    ((u32*)sQ)[256 + tid] = src[256 + tid];
    __syncthreads();
  }

  // ---- flash over this block's 2048-key chunk; wave handles 512 keys ----
  int wslice = ch*2048 + wid*512;
  short8v aq0 = *(const short8v*)&sQ[ln*64 + qd*8];
  short8v aq1 = *(const short8v*)&sQ[ln*64 + 32 + qd*8];
  f32x4 acc[3] = {zf, zf, zf};
  float mrun = -3.0e38f, lrun = 0.f;
  u16* sp = sp4[wid];
  #pragma unroll 1
  for (int kt = 0; kt < 8; ++kt){
    int tb = wslice + kt*64;
    const u16* kb = Kb + (size_t)tb*64;
    const u16* vb = Vc + (size_t)(tb>>8)*48*256 + (tb & 255);
    short8v vf[2][3];
    #pragma unroll
    for (int kc = 0; kc < 2; ++kc)
      #pragma unroll
      for (int dt = 0; dt < 3; ++dt)
        vf[kc][dt] = *(const short8v*)&vb[(dt*16 + ln)*256 + kc*32 + qd*8];
    f32x4 s[4];
    #pragma unroll
    for (int nt = 0; nt < 4; ++nt){
      f32x4 z = zf;
      z = __builtin_amdgcn_mfma_f32_16x16x32_bf16(*(const short8v*)&kb[(nt*16+ln)*64 + qd*8], aq0, z, 0,0,0);
      z = __builtin_amdgcn_mfma_f32_16x16x32_bf16(*(const short8v*)&kb[(nt*16+ln)*64 + 32 + qd*8], aq1, z, 0,0,0);
      s[nt] = z;
    }
    float vmax = s[0][0];
    #pragma unroll
    for (int nt = 0; nt < 4; ++nt)
      #pragma unroll
      for (int r = 0; r < 4; ++r) vmax = fmaxf(vmax, s[nt][r]);
    vmax = fmaxf(vmax, __shfl_xor(vmax, 16));
    vmax = fmaxf(vmax, __shfl_xor(vmax, 32));
    float mnew = fmaxf(mrun, vmax);
    float alpha = __expf(mrun - mnew);
    mrun = mnew;
    float lsum = 0.f;
    #pragma unroll
    for (int nt = 0; nt < 4; ++nt){
      float p0 = __expf(s[nt][0]-mnew), p1 = __expf(s[nt][1]-mnew);
      float p2 = __expf(s[nt][2]-mnew), p3 = __expf(s[nt][3]-mnew);
      lsum += (p0+p1)+(p2+p3);
      uint2 pk; pk.x = pk2(p0,p1); pk.y = pk2(p2,p3);
      *(uint2*)&sp[ln*72 + nt*16 + qd*4] = pk;
    }
    lsum += __shfl_xor(lsum, 16);
    lsum += __shfl_xor(lsum, 32);
    lrun = lrun*alpha + lsum;
    #pragma unroll
    for (int dt = 0; dt < 3; ++dt){
      acc[dt][0] *= alpha; acc[dt][1] *= alpha; acc[dt][2] *= alpha; acc[dt][3] *= alpha;
    }
    short8v pb0 = *(const short8v*)&sp[ln*72 + qd*8];
    short8v pb1 = *(const short8v*)&sp[ln*72 + 32 + qd*8];
    #pragma unroll
    for (int dt = 0; dt < 3; ++dt){
      acc[dt] = __builtin_amdgcn_mfma_f32_16x16x32_bf16(vf[0][dt], pb0, acc[dt], 0,0,0);
      acc[dt] = __builtin_amdgcn_mfma_f32_16x16x32_bf16(vf[1][dt], pb1, acc[dt], 0,0,0);
    }
  }
  // ---- block-internal 4-wave merge, write one partial per (row, chunk) ----
  #pragma unroll
  for (int dt = 0; dt < 3; ++dt)
    #pragma unroll
    for (int r = 0; r < 4; ++r)
      sMg[wid][ln*50 + dt*16 + qd*4 + r] = acc[dt][r];
  if (lane < 16){ sMg[wid][ln*50 + 48] = mrun; sMg[wid][ln*50 + 49] = lrun; }
  __syncthreads();
  {
    int row = tid>>4, j = tid&15;
    int grow = rowbase + row;
    float m0 = sMg[0][row*50+48], m1 = sMg[1][row*50+48];
    float m2 = sMg[2][row*50+48], m3 = sMg[3][row*50+48];
    float mg = fmaxf(fmaxf(m0,m1), fmaxf(m2,m3));
    float e0 = __expf(m0-mg), e1 = __expf(m1-mg), e2 = __expf(m2-mg), e3 = __expf(m3-mg);
    float lg = e0*sMg[0][row*50+49] + e1*sMg[1][row*50+49]
             + e2*sMg[2][row*50+49] + e3*sMg[3][row*50+49];
    if (j == 0){ mC[grow*16 + ch] = mg; lC[grow*16 + ch] = lg; }
    #pragma unroll
    for (int k = 0; k < 3; ++k){
      int d = j + 16*k;
      float a = e0*sMg[0][row*50+d] + e1*sMg[1][row*50+d]
              + e2*sMg[2][row*50+d] + e3*sMg[3][row*50+d];
      aC[(size_t)(grow*16 + ch)*48 + d] = a;
    }
  }
}

// ---------------------------------------------------------------------------
// decoder: 12-step GRU(96) in ONE launch; 4 waves x 16 rows; weights from L2.
__global__ __launch_bounds__(256, 2) void dec_kernel(
    const u16* Dihf, const u16* Dhhf, const float* b_ih, const float* b_hh,
    const float* stateP, const float* pred, const float* obs,
    const float* fc_w, const float* fc_b, float* out)
{
  __shared__ __align__(16) u16 sX[4][16*104];
  const int tid = threadIdx.x, bx = blockIdx.x;
  const int wid = tid>>6, lane = tid&63, qd = lane>>4, ln = lane&15;
  f32x4 zf = {0.f,0.f,0.f,0.f};
  u16* sx = sX[wid];
  int rw = (bx*4 + wid)*16;
  for (int i = lane; i < 1536; i += 64){
    int r = i/96, k = i - r*96;
    int row = rw + r, b20 = row/20;
    float v = (k < 48) ? stateP[b20*48 + k] : pred[(size_t)row*48 + (k-48)];
    sx[r*104 + k] = f2bf(v);
  }
  float fw0[6], fw1[6];
  float biR[6],biZ[6],biN[6],bhR[6],bhZ[6],bhN[6];
  #pragma unroll
  for (int i = 0; i < 6; ++i){
    int d = i*16 + ln;
    fw0[i] = fc_w[d]; fw1[i] = fc_w[96+d];
    biR[i]=b_ih[d]; biZ[i]=b_ih[96+d]; biN[i]=b_ih[192+d];
    bhR[i]=b_hh[d]; bhZ[i]=b_hh[96+d]; bhN[i]=b_hh[192+d];
  }
  float fcb0 = fc_b[0], fcb1 = fc_b[1];
  float pr0[4], pr1[4];
  #pragma unroll
  for (int r = 0; r < 4; ++r){
    int b20 = (rw + qd*4 + r)/20;
    pr0[r] = obs[b20*16 + 14];
    pr1[r] = obs[b20*16 + 15];
  }
  #pragma unroll 1
  for (int t = 0; t < 12; ++t){
    short8v xa0 = *(const short8v*)&sx[ln*104 + qd*8];
    short8v xa1 = *(const short8v*)&sx[ln*104 + 32 + qd*8];
    short8v xa2 = *(const short8v*)&sx[ln*104 + 64 + qd*8];
    const u16* W = (t == 0) ? Dihf : Dhhf;
    f32x4 acc[18];
    #pragma unroll
    for (int i = 0; i < 18; ++i) acc[i] = zf;
    #pragma unroll
    for (int nt = 0; nt < 18; ++nt){
      acc[nt] = __builtin_amdgcn_mfma_f32_16x16x32_bf16(xa0, *(const short8v*)&W[((nt*3+0)*4+qd)*128 + ln*8], acc[nt], 0,0,0);
      acc[nt] = __builtin_amdgcn_mfma_f32_16x16x32_bf16(xa1, *(const short8v*)&W[((nt*3+1)*4+qd)*128 + ln*8], acc[nt], 0,0,0);
      acc[nt] = __builtin_amdgcn_mfma_f32_16x16x32_bf16(xa2, *(const short8v*)&W[((nt*3+2)*4+qd)*128 + ln*8], acc[nt], 0,0,0);
    }
    float px[4] = {0,0,0,0}, py[4] = {0,0,0,0};
    #pragma unroll
    for (int r = 0; r < 4; ++r)
      #pragma unroll
      for (int i = 0; i < 6; ++i){
        int d = i*16 + ln;
        float rr = sigm(acc[i][r]   + biR[i] + bhR[i]);
        float zz = sigm(acc[i+6][r] + biZ[i] + bhZ[i]);
        float nn, hold;
        if (t == 0){
          nn = tanh_fast(acc[i+12][r] + biN[i] + rr*bhN[i]);
          hold = 0.f;
        } else {
          nn = tanh_fast(biN[i] + rr*(acc[i+12][r] + bhN[i]));
          hold = bf2f(sx[(qd*4+r)*104 + d]);
        }
        float hv = (1.f-zz)*nn + zz*hold;
        sx[(qd*4+r)*104 + d] = f2bf(hv);
        px[r] += fw0[i]*hv;
        py[r] += fw1[i]*hv;
      }
    #pragma unroll
    for (int msk = 8; msk >= 1; msk >>= 1)
      #pragma unroll
      for (int r = 0; r < 4; ++r){
        px[r] += __shfl_xor(px[r], msk);
        py[r] += __shfl_xor(py[r], msk);
      }
    #pragma unroll
    for (int r = 0; r < 4; ++r){
      pr0[r] += px[r] + fcb0;
      pr1[r] += py[r] + fcb1;
    }
    if (ln == 0){
      #pragma unroll
      for (int r = 0; r < 4; ++r){
        int row = rw + qd*4 + r;
        out[(size_t)(row*12 + t)*2 + 0] = pr0[r];
        out[(size_t)(row*12 + t)*2 + 1] = pr1[r];
      }
    }
  }
}

// ---------------------------------------------------------------------------
extern "C" void kernel_launch(void* const* d_in, const int* in_sizes, int n_in,
                              void* d_out, int out_size, void* d_ws, size_t ws_size,
                              hipStream_t stream)
{
  const float* past        = (const float*)d_in[0];
  const float* obs         = (const float*)d_in[1];
  const float* conv_w      = (const float*)d_in[2];
  const float* conv_b      = (const float*)d_in[3];
  const float* enc_w_ih    = (const float*)d_in[4];
  const float* enc_w_hh    = (const float*)d_in[5];
  const float* enc_b_ih    = (const float*)d_in[6];
  const float* enc_b_hh    = (const float*)d_in[7];
  const float* memory_past = (const float*)d_in[8];
  const float* memory_fut  = (const float*)d_in[9];
  const float* Wq = (const float*)d_in[10];
  const float* bq = (const float*)d_in[11];
  const float* Wk = (const float*)d_in[12];
  const float* bk = (const float*)d_in[13];
  const float* Wv = (const float*)d_in[14];
  const float* bv = (const float*)d_in[15];
  const float* dec_w_ih = (const float*)d_in[16];
  const float* dec_w_hh = (const float*)d_in[17];
  const float* dec_b_ih = (const float*)d_in[18];
  const float* dec_b_hh = (const float*)d_in[19];
  const float* fc_w = (const float*)d_in[20];
  const float* fc_b = (const float*)d_in[21];
  float* out = (float*)d_out;

  char* ws = (char*)d_ws;
  size_t off = 0;
  auto alloc = [&](size_t bytes){ void* p = ws + off; off += (bytes + 255) & ~(size_t)255; return p; };
  float* stateP = (float*)alloc(512*48*4);
  float* qfA    = (float*)alloc(512*48*4);
  float* qfB    = (float*)alloc(512*48*4);
  u16*   qbB    = (u16*)alloc(512*64*2);
  float* mB[2], *lB[2], *aB[2];
  for (int i = 0; i < 2; ++i){
    mB[i] = (float*)alloc(512*16*4);
    lB[i] = (float*)alloc(512*16*4);
    aB[i] = (float*)alloc((size_t)512*16*48*4);
  }
  float* pred = (float*)alloc((size_t)10240*48*4);
  u16*   Kb   = (u16*)alloc((size_t)32768*64*2);
  u16*   Vc   = (u16*)alloc((size_t)32768*48*2);
  u16*   Dihf = (u16*)alloc(27648*2);
  u16*   Dhhf = (u16*)alloc(27648*2);
  float* qbuf[2] = { qfA, qfB };

  setup_kernel<<<512, 256, 0, stream>>>(
      past, conv_w, conv_b, enc_w_ih, enc_w_hh, enc_b_ih, enc_b_hh,
      memory_past, memory_fut, Wq, bq, Wk, bk, Wv, bv, dec_w_ih, dec_w_hh,
      stateP, qfA, qbB, Kb, Vc, Dihf, Dhhf);

  iter_kernel<<<512, 256, 0, stream>>>(0, 0, qbB, Kb, Vc, Wq, bq,
      qfA, qfA, pred, mB[1], lB[1], aB[1], mB[0], lB[0], aB[0]);
  for (int it = 1; it < 20; ++it){
    int pv = (it-1)&1, cu = it&1;
    iter_kernel<<<512, 256, 0, stream>>>(1, it, qbB, Kb, Vc, Wq, bq,
        qbuf[(it-1)&1], qbuf[it&1], pred, mB[pv], lB[pv], aB[pv], mB[cu], lB[cu], aB[cu]);
  }
  iter_kernel<<<32, 256, 0, stream>>>(2, 20, qbB, Kb, Vc, Wq, bq,
      qbuf[1], qbuf[0], pred, mB[1], lB[1], aB[1], mB[0], lB[0], aB[0]);

  dec_kernel<<<160, 256, 0, stream>>>(Dihf, Dhhf, dec_b_ih, dec_b_hh,
      stateP, pred, obs, fc_w, fc_b, out);
}

// Round 5
// 658.861 us; speedup vs baseline: 5.8717x; 1.5092x over previous
//
#include <hip/hip_runtime.h>

typedef unsigned short u16;
typedef unsigned int u32;
typedef __attribute__((ext_vector_type(8))) short short8v;
typedef __attribute__((ext_vector_type(4))) float f32x4;

#define GLD_LDS(g, l) __builtin_amdgcn_global_load_lds( \
    (const __attribute__((address_space(1))) void*)(g), \
    (__attribute__((address_space(3))) void*)(l), 16, 0, 0)

#define LOG2E 1.44269504f

__device__ __forceinline__ u16 f2bf(float f){
  union { float f; u32 u; } v; v.f = f;
  u32 r = v.u + 0x7FFFu + ((v.u >> 16) & 1u);
  return (u16)(r >> 16);
}
__device__ __forceinline__ float bf2f(u16 h){
  union { u32 u; float f; } v; v.u = ((u32)h) << 16;
  return v.f;
}
// pack two positive floats to bf16x2 (round-half-up) via v_perm
__device__ __forceinline__ u32 pk2(float a, float b){
  union { float f; u32 u; } x, y; x.f = a; y.f = b;
  return __builtin_amdgcn_perm(y.u + 0x8000u, x.u + 0x8000u, 0x07060302u);
}
__device__ __forceinline__ float sigm(float x){ return 1.f/(1.f+__expf(-x)); }
__device__ __forceinline__ float tanh_fast(float x){ return 1.f - 2.f/(1.f+__expf(2.f*x)); }

// ---------------------------------------------------------------------------
// setup: dec/Wq weight frags + KV projection (blocks 0..503) + encoder (504..511)
__global__ __launch_bounds__(256) void setup_kernel(
    const float* past, const float* conv_w, const float* conv_b,
    const float* enc_w_ih, const float* enc_w_hh, const float* enc_b_ih, const float* enc_b_hh,
    const float* memory_past, const float* memory_fut,
    const float* Wq, const float* bq, const float* Wk, const float* bk,
    const float* Wv, const float* bv,
    const float* dec_w_ih, const float* dec_w_hh,
    float* stateP, float* qf, u16* qbB,
    u16* Kb, u16* Vc, u16* Dihf, u16* Dhhf, u16* WqF)
{
  __shared__ __align__(16) char SMEM[61440];
  const int tid = threadIdx.x, bx = blockIdx.x;
  const int wid = tid>>6, lane = tid&63, qd = lane>>4, ln = lane&15;
  f32x4 zf = {0.f,0.f,0.f,0.f};

  if (tid < 108){
    int which = (tid >= 54) ? 1 : 0;
    int e = bx*54 + (tid - which*54);
    const float* src = which ? dec_w_hh : dec_w_ih;
    u16* dst = which ? Dhhf : Dihf;
    int j = e&7, l2 = (e>>3)&15, q2 = (e>>7)&3, tkc = e>>9;
    int kc = tkc % 3, nt = tkc / 3;
    dst[e] = f2bf(src[(nt*16+l2)*96 + kc*32 + q2*8 + j]);
  }
  if (bx < 12){
    int e = bx*256 + tid;
    int j = e&7, l2 = (e>>3)&15, q2 = (e>>7)&3, tkc = e>>9;
    int kc = tkc&1, nt = tkc>>1;
    int g = nt*16+l2, k = kc*32+q2*8+j;
    WqF[e] = (k < 48) ? f2bf(Wq[g*48+k]) : (u16)0;
  }

  if (bx >= 504){
    // ======== ENCODER ========
    int eb = bx - 504;
    u16* sWih = (u16*)(SMEM);
    u16* sWhh = (u16*)(SMEM + 18432);
    u16* sWq  = (u16*)(SMEM + 36864);
    float* sCw = (float*)(SMEM + 43008);
    float* sCb = (float*)(SMEM + 44160);
    float* sPast = (float*)(SMEM + 44352);
    u16* sHbW = (u16*)(SMEM + 48448 + wid*2304);
    for (int e0 = tid; e0 < 21504; e0 += 256){
      int e = e0; const float* src; u16* dst;
      if (e < 9216){ src = enc_w_ih; dst = sWih; }
      else if (e < 18432){ e -= 9216; src = enc_w_hh; dst = sWhh; }
      else { e -= 18432; src = Wq; dst = sWq; }
      int j = e&7, l2 = (e>>3)&15, q2 = (e>>7)&3, tkc = e>>9;
      int kc = tkc&1, nt = tkc>>1;
      int g = nt*16+l2, k = kc*32+q2*8+j;
      dst[e] = (k < 48) ? f2bf(src[g*48+k]) : (u16)0;
    }
    for (int i = tid; i < 288; i += 256) sCw[i] = conv_w[i];
    if (tid < 48) sCb[tid] = conv_b[tid];
    for (int i = tid; i < 1024; i += 256) sPast[i] = past[eb*1024 + i];
    __syncthreads();
    short8v aE[8][2];
    {
      const float* pr = &sPast[(wid*16 + ln)*16];
      for (int t = 0; t < 8; ++t)
        for (int kc = 0; kc < 2; ++kc){
          union { short8v v; u16 h[8]; } u;
          #pragma unroll
          for (int j = 0; j < 8; ++j){
            int d = kc*32 + qd*8 + j;
            float a = 0.f;
            if (d < 48){
              a = sCb[d];
              #pragma unroll
              for (int kt = 0; kt < 3; ++kt){
                int tau = t + kt - 1;
                if (tau >= 0 && tau < 8){
                  a += pr[tau*2+0]*sCw[d*6+kt];
                  a += pr[tau*2+1]*sCw[d*6+3+kt];
                }
              }
              a = fmaxf(a, 0.f);
            }
            u.h[j] = (d < 48) ? f2bf(a) : (u16)0;
          }
          aE[t][kc] = u.v;
        }
    }
    for (int i = lane; i < 576; i += 64) ((u32*)sHbW)[i] = 0;
    float biR[3],biZ[3],biN[3],bhR[3],bhZ[3],bhN[3];
    #pragma unroll
    for (int i = 0; i < 3; ++i){
      int d = i*16 + ln;
      biR[i]=enc_b_ih[d]; biZ[i]=enc_b_ih[48+d]; biN[i]=enc_b_ih[96+d];
      bhR[i]=enc_b_hh[d]; bhZ[i]=enc_b_hh[48+d]; bhN[i]=enc_b_hh[96+d];
    }
    float hreg[3][4];
    #pragma unroll
    for (int i=0;i<3;++i) for (int r=0;r<4;++r) hreg[i][r]=0.f;
    int r0 = eb*64 + wid*16;
    #pragma unroll 1
    for (int t = 0; t < 8; ++t){
      short8v aH0 = *(const short8v*)&sHbW[ln*72 + qd*8];
      short8v aH1 = *(const short8v*)&sHbW[ln*72 + 32 + qd*8];
      f32x4 gI[9], gH[9];
      #pragma unroll
      for (int nt = 0; nt < 9; ++nt){ gI[nt] = zf; gH[nt] = zf; }
      #pragma unroll
      for (int nt = 0; nt < 9; ++nt){
        gI[nt] = __builtin_amdgcn_mfma_f32_16x16x32_bf16(aE[t][0], *(const short8v*)&sWih[((nt*2+0)*4+qd)*128 + ln*8], gI[nt], 0,0,0);
        gI[nt] = __builtin_amdgcn_mfma_f32_16x16x32_bf16(aE[t][1], *(const short8v*)&sWih[((nt*2+1)*4+qd)*128 + ln*8], gI[nt], 0,0,0);
        gH[nt] = __builtin_amdgcn_mfma_f32_16x16x32_bf16(aH0, *(const short8v*)&sWhh[((nt*2+0)*4+qd)*128 + ln*8], gH[nt], 0,0,0);
        gH[nt] = __builtin_amdgcn_mfma_f32_16x16x32_bf16(aH1, *(const short8v*)&sWhh[((nt*2+1)*4+qd)*128 + ln*8], gH[nt], 0,0,0);
      }
      #pragma unroll
      for (int i3 = 0; i3 < 3; ++i3)
        #pragma unroll
        for (int r = 0; r < 4; ++r){
          float rr = sigm(gI[i3][r]+biR[i3] + gH[i3][r]+bhR[i3]);
          float zz = sigm(gI[i3+3][r]+biZ[i3] + gH[i3+3][r]+bhZ[i3]);
          float nn = tanh_fast(gI[i3+6][r]+biN[i3] + rr*(gH[i3+6][r]+bhN[i3]));
          float hv = (1.f-zz)*nn + zz*hreg[i3][r];
          hreg[i3][r] = hv;
          sHbW[(qd*4+r)*72 + i3*16 + ln] = f2bf(hv);
        }
    }
    #pragma unroll
    for (int i3 = 0; i3 < 3; ++i3)
      #pragma unroll
      for (int r = 0; r < 4; ++r)
        stateP[(r0+qd*4+r)*48 + i3*16 + ln] = hreg[i3][r];
    short8v aH0 = *(const short8v*)&sHbW[ln*72 + qd*8];
    short8v aH1 = *(const short8v*)&sHbW[ln*72 + 32 + qd*8];
    f32x4 q3[3];
    #pragma unroll
    for (int nt = 0; nt < 3; ++nt){
      q3[nt] = zf;
      q3[nt] = __builtin_amdgcn_mfma_f32_16x16x32_bf16(aH0, *(const short8v*)&sWq[((nt*2+0)*4+qd)*128 + ln*8], q3[nt], 0,0,0);
      q3[nt] = __builtin_amdgcn_mfma_f32_16x16x32_bf16(aH1, *(const short8v*)&sWq[((nt*2+1)*4+qd)*128 + ln*8], q3[nt], 0,0,0);
    }
    #pragma unroll
    for (int nt = 0; nt < 3; ++nt)
      #pragma unroll
      for (int r = 0; r < 4; ++r){
        int row = r0 + qd*4 + r, d = nt*16 + ln;
        float v = q3[nt][r] + bq[d];
        qf[row*48 + d] = v;
        qbB[row*64 + d] = f2bf(v * LOG2E);
      }
    #pragma unroll
    for (int r = 0; r < 4; ++r)
      if (ln < 8) *(u32*)&qbB[(r0+qd*4+r)*64 + 48 + ln*2] = 0;
  } else {
    // ======== KV projection ========
    u16* sWkF = (u16*)(SMEM);
    u16* sWvF = (u16*)(SMEM + 6144);
    u16* smp  = (u16*)(SMEM + 12288 + wid*2304);
    u16* smf  = (u16*)(SMEM + 21504 + wid*2304);
    for (int e0 = tid; e0 < 6144; e0 += 256){
      int e = e0; const float* src; u16* dst;
      if (e < 3072){ src = Wk; dst = sWkF; } else { e -= 3072; src = Wv; dst = sWvF; }
      int j = e&7, l2 = (e>>3)&15, q2 = (e>>7)&3, tkc = e>>9;
      int kc = tkc&1, nt = tkc>>1;
      int g = nt*16+l2, k = kc*32+q2*8+j;
      dst[e] = (k < 48) ? f2bf(src[g*48+k]) : (u16)0;
    }
    __syncthreads();
    int ntile = (bx < 8) ? 2 : 1;
    for (int tt = 0; tt < ntile; ++tt){
      int tile = (tt == 0) ? bx : (504 + bx);
      int r0 = tile*64 + wid*16;
      for (int i = lane; i < 576; i += 64){ ((u32*)smp)[i] = 0; ((u32*)smf)[i] = 0; }
      for (int i = lane; i < 768; i += 64){
        int r = i/48, c = i - r*48;
        smp[r*72+c] = f2bf(memory_past[(size_t)r0*48 + i]);
        smf[r*72+c] = f2bf(memory_fut[(size_t)r0*48 + i]);
      }
      short8v aP0 = *(const short8v*)&smp[ln*72 + qd*8];
      short8v aP1 = *(const short8v*)&smp[ln*72 + 32 + qd*8];
      short8v aF0 = *(const short8v*)&smf[ln*72 + qd*8];
      short8v aF1 = *(const short8v*)&smf[ln*72 + 32 + qd*8];
      f32x4 k3[3], v3[3];
      #pragma unroll
      for (int nt = 0; nt < 3; ++nt){ k3[nt] = zf; v3[nt] = zf; }
      #pragma unroll
      for (int nt = 0; nt < 3; ++nt){
        k3[nt] = __builtin_amdgcn_mfma_f32_16x16x32_bf16(aP0, *(const short8v*)&sWkF[((nt*2+0)*4+qd)*128 + ln*8], k3[nt], 0,0,0);
        k3[nt] = __builtin_amdgcn_mfma_f32_16x16x32_bf16(aP1, *(const short8v*)&sWkF[((nt*2+1)*4+qd)*128 + ln*8], k3[nt], 0,0,0);
        v3[nt] = __builtin_amdgcn_mfma_f32_16x16x32_bf16(aF0, *(const short8v*)&sWvF[((nt*2+0)*4+qd)*128 + ln*8], v3[nt], 0,0,0);
        v3[nt] = __builtin_amdgcn_mfma_f32_16x16x32_bf16(aF1, *(const short8v*)&sWvF[((nt*2+1)*4+qd)*128 + ln*8], v3[nt], 0,0,0);
      }
      #pragma unroll
      for (int nt = 0; nt < 3; ++nt)
        #pragma unroll
        for (int r = 0; r < 4; ++r){
          int key = r0 + qd*4 + r, d = nt*16 + ln;
          Kb[(size_t)key*64 + d] = f2bf(k3[nt][r] + bk[d]);
          Vc[((size_t)(key>>8)*48 + d)*256 + (key&255)] = f2bf(v3[nt][r] + bv[d]);
        }
      #pragma unroll
      for (int r = 0; r < 4; ++r)
        if (ln < 8){ int key = r0 + qd*4 + r; *(u32*)&Kb[(size_t)key*64 + 48 + ln*2] = 0; }
    }
  }
}

// ---------------------------------------------------------------------------
// iter: [combine prev -> pred/c/q] + [flash partials cur].
// mode 0: flash only (grid 256 = 16rg x 16ch); mode 1: both (grid 256);
// mode 2: final combine only (grid 32).
__global__ __launch_bounds__(256) void iter_kernel(int mode, int it,
    const u16* qbB, const u16* Kb, const u16* Vc, const u16* WqF, const float* bq,
    const float* qfP, float* qfC, float* pred,
    const float* mP, const float* lP, const float* aP,
    float* mC, float* lC, float* aC)
{
  __shared__ __align__(16) u16 sQ[32*64];
  __shared__ __align__(16) u16 sp8[8][16*72];
  __shared__ float sMg[4][32*50];
  __shared__ float sWc[32*16];
  __shared__ float sLg[32];
  __shared__ __align__(16) u16 sCb[32*72];
  const int tid = threadIdx.x, bx = blockIdx.x;
  const int wid = tid>>6, lane = tid&63, qd = lane>>4, ln = lane&15;
  f32x4 zf = {0.f,0.f,0.f,0.f};

  if (mode == 2){
    int lrow = tid>>4, j = tid&15;
    int row = bx*16 + lrow;
    float m = mP[row*16 + j], l = lP[row*16 + j];
    float mg = m;
    #pragma unroll
    for (int k = 1; k < 16; k <<= 1) mg = fmaxf(mg, __shfl_xor(mg, k));
    float w = exp2f(m - mg);
    float wl = w*l;
    #pragma unroll
    for (int k = 1; k < 16; k <<= 1) wl += __shfl_xor(wl, k);
    sWc[lrow*16 + j] = w;
    if (j == 0) sLg[lrow] = wl;
    __syncthreads();
    float lg = sLg[lrow];
    #pragma unroll
    for (int k2 = 0; k2 < 3; ++k2){
      int d = j + k2*16;
      float a = 0.f;
      #pragma unroll 4
      for (int c = 0; c < 16; ++c) a += sWc[lrow*16+c]*aP[(size_t)(row*16+c)*48 + d];
      pred[(size_t)(row*20 + 19)*48 + d] = a / lg;
    }
    return;
  }

  const int rg = bx>>4, ch = bx&15;
  const int rowbase = rg*32;

  if (mode == 1){
    // ---- combine prev partials ----
    int row = tid>>3, jj = tid&7, grow = rowbase + row;
    float m0 = mP[grow*16 + jj*2], m1 = mP[grow*16 + jj*2+1];
    float l0 = lP[grow*16 + jj*2], l1 = lP[grow*16 + jj*2+1];
    float mg = fmaxf(m0, m1);
    #pragma unroll
    for (int k = 1; k < 8; k <<= 1) mg = fmaxf(mg, __shfl_xor(mg, k));
    float w0 = exp2f(m0 - mg), w1 = exp2f(m1 - mg);
    float wl = w0*l0 + w1*l1;
    #pragma unroll
    for (int k = 1; k < 8; k <<= 1) wl += __shfl_xor(wl, k);
    sWc[row*16 + jj*2] = w0; sWc[row*16 + jj*2+1] = w1;
    if (jj == 0) sLg[row] = wl;
    __syncthreads();
    float lg = sLg[row];
    int d0 = jj*6;
    float aa[6] = {0,0,0,0,0,0};
    #pragma unroll 4
    for (int c = 0; c < 16; ++c){
      float w = sWc[row*16 + c];
      const float* ap = aP + (size_t)(grow*16 + c)*48 + d0;
      #pragma unroll
      for (int d6 = 0; d6 < 6; ++d6) aa[d6] += w*ap[d6];
    }
    #pragma unroll
    for (int d6 = 0; d6 < 6; ++d6){
      int d = d0 + d6;
      float a = aa[d6] / lg;
      if (ch == 0) pred[(size_t)(grow*20 + (it-1))*48 + d] = a;
      sCb[row*72 + d] = f2bf(qfP[grow*48 + d] + a);
    }
    { int r2 = tid>>3, p = tid&7; ((u32*)&sCb[r2*72 + 48])[p] = 0; }
    __syncthreads();
    // ---- q projection via MFMA (waves 0,1), pad sQ (waves 2,3) ----
    if (wid < 2){
      short8v ac0 = *(const short8v*)&sCb[(wid*16+ln)*72 + qd*8];
      short8v ac1 = *(const short8v*)&sCb[(wid*16+ln)*72 + 32 + qd*8];
      f32x4 q3[3];
      #pragma unroll
      for (int nt = 0; nt < 3; ++nt){
        q3[nt] = zf;
        q3[nt] = __builtin_amdgcn_mfma_f32_16x16x32_bf16(ac0, *(const short8v*)&WqF[((nt*2+0)*4+qd)*128 + ln*8], q3[nt], 0,0,0);
        q3[nt] = __builtin_amdgcn_mfma_f32_16x16x32_bf16(ac1, *(const short8v*)&WqF[((nt*2+1)*4+qd)*128 + ln*8], q3[nt], 0,0,0);
      }
      #pragma unroll
      for (int nt = 0; nt < 3; ++nt)
        #pragma unroll
        for (int r = 0; r < 4; ++r){
          int lr = wid*16 + qd*4 + r, d = nt*16 + ln;
          float v = q3[nt][r] + bq[d];
          if (ch == 0) qfC[(rowbase + lr)*48 + d] = v;
          sQ[lr*64 + d] = f2bf(v * LOG2E);
        }
    } else {
      for (int i = tid-128; i < 256; i += 128){
        int r2 = i>>3, p = i&7;
        ((u32*)&sQ[r2*64 + 48])[p] = 0;
      }
    }
    __syncthreads();
  } else {
    const u32* src = (const u32*)(qbB + rowbase*64);
    ((u32*)sQ)[tid]       = src[tid];
    ((u32*)sQ)[256 + tid] = src[256 + tid];
    ((u32*)sQ)[512 + tid] = src[512 + tid];
    ((u32*)sQ)[768 + tid] = src[768 + tid];
    __syncthreads();
  }

  // ---- flash: wave handles 32 rows x 512 keys (8 kt of 64) ----
  const int wslice = ch*2048 + wid*512;
  short8v aq[2][2];
  #pragma unroll
  for (int rt = 0; rt < 2; ++rt)
    #pragma unroll
    for (int kc = 0; kc < 2; ++kc)
      aq[rt][kc] = *(const short8v*)&sQ[(rt*16+ln)*64 + kc*32 + qd*8];
  f32x4 acc[2][3];
  #pragma unroll
  for (int rt = 0; rt < 2; ++rt) for (int dt = 0; dt < 3; ++dt) acc[rt][dt] = zf;
  float mrun[2] = {-3.0e38f, -3.0e38f}, lrun[2] = {0.f, 0.f};
  u16* spb[2] = { sp8[wid*2], sp8[wid*2+1] };

  #pragma unroll
  for (int kt = 0; kt < 8; ++kt){
    const int tb = wslice + kt*64;
    const u16* kb = Kb + (size_t)tb*64;
    const u16* vb = Vc + (size_t)(tb>>8)*48*256 + (tb & 255);
    short8v kf[4][2], vf[2][3];
    #pragma unroll
    for (int nt = 0; nt < 4; ++nt)
      #pragma unroll
      for (int kc = 0; kc < 2; ++kc)
        kf[nt][kc] = *(const short8v*)&kb[(nt*16+ln)*64 + kc*32 + qd*8];
    #pragma unroll
    for (int kc = 0; kc < 2; ++kc)
      #pragma unroll
      for (int dt = 0; dt < 3; ++dt)
        vf[kc][dt] = *(const short8v*)&vb[(dt*16+ln)*256 + kc*32 + qd*8];
    f32x4 s[2][4];
    #pragma unroll
    for (int rt = 0; rt < 2; ++rt)
      #pragma unroll
      for (int nt = 0; nt < 4; ++nt){
        f32x4 z = zf;
        z = __builtin_amdgcn_mfma_f32_16x16x32_bf16(kf[nt][0], aq[rt][0], z, 0,0,0);
        z = __builtin_amdgcn_mfma_f32_16x16x32_bf16(kf[nt][1], aq[rt][1], z, 0,0,0);
        s[rt][nt] = z;
      }
    #pragma unroll
    for (int rt = 0; rt < 2; ++rt){
      float vmax = fmaxf(fmaxf(fmaxf(s[rt][0][0], s[rt][0][1]), fmaxf(s[rt][0][2], s[rt][0][3])),
                   fmaxf(fmaxf(s[rt][1][0], s[rt][1][1]), fmaxf(s[rt][1][2], s[rt][1][3])));
      vmax = fmaxf(vmax, fmaxf(fmaxf(fmaxf(s[rt][2][0], s[rt][2][1]), fmaxf(s[rt][2][2], s[rt][2][3])),
                   fmaxf(fmaxf(s[rt][3][0], s[rt][3][1]), fmaxf(s[rt][3][2], s[rt][3][3]))));
      vmax = fmaxf(vmax, __shfl_xor(vmax, 16));
      vmax = fmaxf(vmax, __shfl_xor(vmax, 32));
      float mnew = fmaxf(mrun[rt], vmax);
      float alpha = exp2f(mrun[rt] - mnew);
      mrun[rt] = mnew;
      u16* sp = spb[rt];
      float lsum = 0.f;
      #pragma unroll
      for (int nt = 0; nt < 4; ++nt){
        float p0 = exp2f(s[rt][nt][0]-mnew), p1 = exp2f(s[rt][nt][1]-mnew);
        float p2 = exp2f(s[rt][nt][2]-mnew), p3 = exp2f(s[rt][nt][3]-mnew);
        lsum += (p0+p1)+(p2+p3);
        uint2 pk; pk.x = pk2(p0,p1); pk.y = pk2(p2,p3);
        *(uint2*)&sp[ln*72 + nt*16 + qd*4] = pk;
      }
      lsum += __shfl_xor(lsum, 16);
      lsum += __shfl_xor(lsum, 32);
      lrun[rt] = lrun[rt]*alpha + lsum;
      #pragma unroll
      for (int dt = 0; dt < 3; ++dt){
        acc[rt][dt][0] *= alpha; acc[rt][dt][1] *= alpha;
        acc[rt][dt][2] *= alpha; acc[rt][dt][3] *= alpha;
      }
      short8v pb0 = *(const short8v*)&sp[ln*72 + qd*8];
      short8v pb1 = *(const short8v*)&sp[ln*72 + 32 + qd*8];
      #pragma unroll
      for (int dt = 0; dt < 3; ++dt){
        acc[rt][dt] = __builtin_amdgcn_mfma_f32_16x16x32_bf16(vf[0][dt], pb0, acc[rt][dt], 0,0,0);
        acc[rt][dt] = __builtin_amdgcn_mfma_f32_16x16x32_bf16(vf[1][dt], pb1, acc[rt][dt], 0,0,0);
      }
    }
  }
  // ---- 4-wave merge -> one partial per (row, chunk) ----
  #pragma unroll
  for (int rt = 0; rt < 2; ++rt)
    #pragma unroll
    for (int dt = 0; dt < 3; ++dt)
      #pragma unroll
      for (int r = 0; r < 4; ++r)
        sMg[wid][(rt*16+ln)*50 + dt*16 + qd*4 + r] = acc[rt][dt][r];
  if (lane < 16){
    sMg[wid][ln*50 + 48] = mrun[0]; sMg[wid][ln*50 + 49] = lrun[0];
    sMg[wid][(16+ln)*50 + 48] = mrun[1]; sMg[wid][(16+ln)*50 + 49] = lrun[1];
  }
  __syncthreads();
  {
    int row = tid>>3, jj = tid&7, grow = rowbase + row;
    float m0 = sMg[0][row*50+48], m1 = sMg[1][row*50+48];
    float m2 = sMg[2][row*50+48], m3 = sMg[3][row*50+48];
    float mg = fmaxf(fmaxf(m0,m1), fmaxf(m2,m3));
    float e0 = exp2f(m0-mg), e1 = exp2f(m1-mg), e2 = exp2f(m2-mg), e3 = exp2f(m3-mg);
    float lg = e0*sMg[0][row*50+49] + e1*sMg[1][row*50+49]
             + e2*sMg[2][row*50+49] + e3*sMg[3][row*50+49];
    if (jj == 0){ mC[grow*16 + ch] = mg; lC[grow*16 + ch] = lg; }
    int d0 = jj*6;
    #pragma unroll
    for (int d6 = 0; d6 < 6; ++d6){
      int d = d0 + d6;
      aC[(size_t)(grow*16 + ch)*48 + d] =
          e0*sMg[0][row*50+d] + e1*sMg[1][row*50+d]
        + e2*sMg[2][row*50+d] + e3*sMg[3][row*50+d];
    }
  }
}

// ---------------------------------------------------------------------------
// decoder: 12-step GRU(96); weights staged in LDS (Dihf for t=0, then Dhhf).
__global__ __launch_bounds__(128) void dec_kernel(
    const u16* Dihf, const u16* Dhhf, const float* b_ih, const float* b_hh,
    const float* stateP, const float* pred, const float* obs,
    const float* fc_w, const float* fc_b, float* out)
{
  __shared__ __align__(16) u16 sW[27648];
  __shared__ __align__(16) u16 sX[2][16*104];
  const int tid = threadIdx.x, bx = blockIdx.x;
  const int wid = tid>>6, lane = tid&63, qd = lane>>4, ln = lane&15;
  f32x4 zf = {0.f,0.f,0.f,0.f};
  for (int i = wid; i < 54; i += 2)
    GLD_LDS((const char*)Dihf + i*1024 + lane*16, (char*)sW + i*1024);
  u16* sx = sX[wid];
  int rw = (bx*2 + wid)*16;
  for (int i = lane; i < 1536; i += 64){
    int r = i/96, k = i - r*96;
    int row = rw + r, b20 = row/20;
    float v = (k < 48) ? stateP[b20*48 + k] : pred[(size_t)row*48 + (k-48)];
    sx[r*104 + k] = f2bf(v);
  }
  float fw0[6], fw1[6];
  float biR[6],biZ[6],biN[6],bhR[6],bhZ[6],bhN[6];
  #pragma unroll
  for (int i = 0; i < 6; ++i){
    int d = i*16 + ln;
    fw0[i] = fc_w[d]; fw1[i] = fc_w[96+d];
    biR[i]=b_ih[d]; biZ[i]=b_ih[96+d]; biN[i]=b_ih[192+d];
    bhR[i]=b_hh[d]; bhZ[i]=b_hh[96+d]; bhN[i]=b_hh[192+d];
  }
  float fcb0 = fc_b[0], fcb1 = fc_b[1];
  float pr0[4], pr1[4];
  #pragma unroll
  for (int r = 0; r < 4; ++r){
    int b20 = (rw + qd*4 + r)/20;
    pr0[r] = obs[b20*16 + 14];
    pr1[r] = obs[b20*16 + 15];
  }
  __syncthreads();
  #pragma unroll 1
  for (int t = 0; t < 12; ++t){
    if (t == 1){
      __syncthreads();
      for (int i = wid; i < 54; i += 2)
        GLD_LDS((const char*)Dhhf + i*1024 + lane*16, (char*)sW + i*1024);
      __syncthreads();
    }
    short8v xa0 = *(const short8v*)&sx[ln*104 + qd*8];
    short8v xa1 = *(const short8v*)&sx[ln*104 + 32 + qd*8];
    short8v xa2 = *(const short8v*)&sx[ln*104 + 64 + qd*8];
    f32x4 acc[18];
    #pragma unroll
    for (int i = 0; i < 18; ++i) acc[i] = zf;
    #pragma unroll
    for (int nt = 0; nt < 18; ++nt){
      acc[nt] = __builtin_amdgcn_mfma_f32_16x16x32_bf16(xa0, *(const short8v*)&sW[((nt*3+0)*4+qd)*128 + ln*8], acc[nt], 0,0,0);
      acc[nt] = __builtin_amdgcn_mfma_f32_16x16x32_bf16(xa1, *(const short8v*)&sW[((nt*3+1)*4+qd)*128 + ln*8], acc[nt], 0,0,0);
      acc[nt] = __builtin_amdgcn_mfma_f32_16x16x32_bf16(xa2, *(const short8v*)&sW[((nt*3+2)*4+qd)*128 + ln*8], acc[nt], 0,0,0);
    }
    float px[4] = {0,0,0,0}, py[4] = {0,0,0,0};
    #pragma unroll
    for (int r = 0; r < 4; ++r)
      #pragma unroll
      for (int i = 0; i < 6; ++i){
        int d = i*16 + ln;
        float rr = sigm(acc[i][r]   + biR[i] + bhR[i]);
        float zz = sigm(acc[i+6][r] + biZ[i] + bhZ[i]);
        float nn, hold;
        if (t == 0){
          nn = tanh_fast(acc[i+12][r] + biN[i] + rr*bhN[i]);
          hold = 0.f;
        } else {
          nn = tanh_fast(biN[i] + rr*(acc[i+12][r] + bhN[i]));
          hold = bf2f(sx[(qd*4+r)*104 + d]);
        }
        float hv = (1.f-zz)*nn + zz*hold;
        sx[(qd*4+r)*104 + d] = f2bf(hv);
        px[r] += fw0[i]*hv;
        py[r] += fw1[i]*hv;
      }
    #pragma unroll
    for (int msk = 8; msk >= 1; msk >>= 1)
      #pragma unroll
      for (int r = 0; r < 4; ++r){
        px[r] += __shfl_xor(px[r], msk);
        py[r] += __shfl_xor(py[r], msk);
      }
    #pragma unroll
    for (int r = 0; r < 4; ++r){
      pr0[r] += px[r] + fcb0;
      pr1[r] += py[r] + fcb1;
    }
    if (ln == 0){
      #pragma unroll
      for (int r = 0; r < 4; ++r){
        int row = rw + qd*4 + r;
        out[(size_t)(row*12 + t)*2 + 0] = pr0[r];
        out[(size_t)(row*12 + t)*2 + 1] = pr1[r];
      }
    }
  }
}

// ---------------------------------------------------------------------------
extern "C" void kernel_launch(void* const* d_in, const int* in_sizes, int n_in,
                              void* d_out, int out_size, void* d_ws, size_t ws_size,
                              hipStream_t stream)
{
  const float* past        = (const float*)d_in[0];
  const float* obs         = (const float*)d_in[1];
  const float* conv_w      = (const float*)d_in[2];
  const float* conv_b      = (const float*)d_in[3];
  const float* enc_w_ih    = (const float*)d_in[4];
  const float* enc_w_hh    = (const float*)d_in[5];
  const float* enc_b_ih    = (const float*)d_in[6];
  const float* enc_b_hh    = (const float*)d_in[7];
  const float* memory_past = (const float*)d_in[8];
  const float* memory_fut  = (const float*)d_in[9];
  const float* Wq = (const float*)d_in[10];
  const float* bq = (const float*)d_in[11];
  const float* Wk = (const float*)d_in[12];
  const float* bk = (const float*)d_in[13];
  const float* Wv = (const float*)d_in[14];
  const float* bv = (const float*)d_in[15];
  const float* dec_w_ih = (const float*)d_in[16];
  const float* dec_w_hh = (const float*)d_in[17];
  const float* dec_b_ih = (const float*)d_in[18];
  const float* dec_b_hh = (const float*)d_in[19];
  const float* fc_w = (const float*)d_in[20];
  const float* fc_b = (const float*)d_in[21];
  float* out = (float*)d_out;

  char* ws = (char*)d_ws;
  size_t off = 0;
  auto alloc = [&](size_t bytes){ void* p = ws + off; off += (bytes + 255) & ~(size_t)255; return p; };
  float* stateP = (float*)alloc(512*48*4);
  float* qfA    = (float*)alloc(512*48*4);
  float* qfB    = (float*)alloc(512*48*4);
  u16*   qbB    = (u16*)alloc(512*64*2);
  float* mB[2], *lB[2], *aB[2];
  for (int i = 0; i < 2; ++i){
    mB[i] = (float*)alloc(512*16*4);
    lB[i] = (float*)alloc(512*16*4);
    aB[i] = (float*)alloc((size_t)512*16*48*4);
  }
  float* pred = (float*)alloc((size_t)10240*48*4);
  u16*   Kb   = (u16*)alloc((size_t)32768*64*2);
  u16*   Vc   = (u16*)alloc((size_t)32768*48*2);
  u16*   Dihf = (u16*)alloc(27648*2);
  u16*   Dhhf = (u16*)alloc(27648*2);
  u16*   WqF  = (u16*)alloc(3072*2);
  float* qbuf[2] = { qfA, qfB };

  setup_kernel<<<512, 256, 0, stream>>>(
      past, conv_w, conv_b, enc_w_ih, enc_w_hh, enc_b_ih, enc_b_hh,
      memory_past, memory_fut, Wq, bq, Wk, bk, Wv, bv, dec_w_ih, dec_w_hh,
      stateP, qfA, qbB, Kb, Vc, Dihf, Dhhf, WqF);

  iter_kernel<<<256, 256, 0, stream>>>(0, 0, qbB, Kb, Vc, WqF, bq,
      qfA, qfA, pred, mB[1], lB[1], aB[1], mB[0], lB[0], aB[0]);
  for (int it = 1; it < 20; ++it){
    int pv = (it-1)&1, cu = it&1;
    iter_kernel<<<256, 256, 0, stream>>>(1, it, qbB, Kb, Vc, WqF, bq,
        qbuf[pv], qbuf[cu], pred, mB[pv], lB[pv], aB[pv], mB[cu], lB[cu], aB[cu]);
  }
  iter_kernel<<<32, 256, 0, stream>>>(2, 20, qbB, Kb, Vc, WqF, bq,
      qbuf[1], qbuf[0], pred, mB[1], lB[1], aB[1], mB[0], lB[0], aB[0]);

  dec_kernel<<<320, 128, 0, stream>>>(Dihf, Dhhf, dec_b_ih, dec_b_hh,
      stateP, pred, obs, fc_w, fc_b, out);
}